// Round 1
// baseline (356.681 us; speedup 1.0000x reference)
//
#include <hip/hip_runtime.h>

namespace {
constexpr int kB = 16;
constexpr int kMAXLEN = 1024;
constexpr int kPE = 256;
constexpr int kN = 1024;
constexpr int kEMB = 256;
constexpr int kC = 128;
constexpr float kEPS = 1e-5f;

// workspace offsets in floats
constexpr size_t OFF_FEATPART = 0;                       // 16*8*256 = 32768
constexpr size_t OFF_M1       = 32768;                   // 16*512 = 8192
constexpr size_t OFF_X        = 65536;                   // 16*1024*128 = 2097152
constexpr size_t OFF_QK       = OFF_X   + 2097152;       // q|k, later reused as z
constexpr size_t OFF_TCUR     = OFF_QK  + 2097152;
constexpr size_t OFF_TNEXT    = OFF_TCUR+ 2097152;
constexpr size_t OFF_ATT      = OFF_TNEXT+2097152;       // 16*1024*1024
constexpr size_t OFF_PMAX     = OFF_ATT + 16777216;      // 16*16*1024
constexpr size_t OFF_PSUM     = OFF_PMAX+ 262144;
constexpr size_t OFF_CMAX     = OFF_PSUM+ 262144;        // 16*1024
constexpr size_t OFF_CINV     = OFF_CMAX+ 16384;
} // namespace

// ---- 1. embedding gather partial sums: featpart[b][chunk][e] ----
__global__ __launch_bounds__(256) void k_embsum(const int* __restrict__ data,
                                                const float* __restrict__ emb,
                                                float* __restrict__ featpart) {
  const int b = blockIdx.x, ch = blockIdx.y;   // 16 x 8
  const int e = threadIdx.x;                   // 256
  const int* row = data + b * (kMAXLEN + kPE) + ch * 128;
  float acc = 0.f;
#pragma unroll 4
  for (int l = 0; l < 128; ++l) {
    acc += emb[(size_t)row[l] * kEMB + e];
  }
  featpart[((b * 8 + ch) << 8) + e] = acc;
}

// ---- 2. BN over batch of concat[feat, inp2] -> m1 (16,512) ----
__global__ __launch_bounds__(512) void k_bn_feat(const float* __restrict__ featpart,
                                                 const int* __restrict__ data,
                                                 const float* __restrict__ g1,
                                                 const float* __restrict__ b1,
                                                 float* __restrict__ m1) {
  const int j = threadIdx.x;  // 0..511
  float v[kB];
  if (j < kPE) {
    const float pe = sinf((float)j);
#pragma unroll
    for (int b = 0; b < kB; ++b) {
      float s = 0.f;
      for (int ch = 0; ch < 8; ++ch) s += featpart[((b * 8 + ch) << 8) + j];
      v[b] = s * (1.f / 1024.f) + pe;
    }
  } else {
    const int e = j - kPE;
    const float pe = sinf((float)e);
#pragma unroll
    for (int b = 0; b < kB; ++b)
      v[b] = (float)data[b * (kMAXLEN + kPE) + kMAXLEN + e] + pe;
  }
  float s = 0.f;
#pragma unroll
  for (int b = 0; b < kB; ++b) s += v[b];
  const float mean = s * (1.f / kB);
  float s2 = 0.f;
#pragma unroll
  for (int b = 0; b < kB; ++b) { float d = v[b] - mean; s2 += d * d; }
  const float inv = rsqrtf(s2 * (1.f / kB) + kEPS);
  const float g = g1[j], bb = b1[j];
#pragma unroll
  for (int b = 0; b < kB; ++b) m1[b * 512 + j] = (v[b] - mean) * inv * g + bb;
}

// ---- 3. go = relu(m1 @ w_go + b_go) -> x[...,0:64]. 1 thread = 1 col, 16 rows ----
__global__ __launch_bounds__(256) void k_go_gemm(const float* __restrict__ m1,
                                                 const float* __restrict__ w_go,
                                                 const float* __restrict__ b_go,
                                                 float* __restrict__ x) {
  __shared__ float m1s[kB * 512];
  for (int it = 0; it < 32; ++it) {
    int e = it * 256 + threadIdx.x;
    m1s[e] = m1[e];
  }
  __syncthreads();
  const int col = blockIdx.x * 256 + threadIdx.x;  // 0..65535
  float acc[kB];
  const float bg = b_go[col];
#pragma unroll
  for (int b = 0; b < kB; ++b) acc[b] = bg;
#pragma unroll 4
  for (int k = 0; k < 512; ++k) {
    const float w = w_go[(size_t)k * 65536 + col];
#pragma unroll
    for (int b = 0; b < kB; ++b) acc[b] += m1s[b * 512 + k] * w;
  }
  const int n = col >> 6, c = col & 63;
#pragma unroll
  for (int b = 0; b < kB; ++b) {
    float vv = acc[b];
    vv = vv > 0.f ? vv : 0.f;
    x[((size_t)(b * kN + n)) * kC + c] = vv;
  }
}

// ---- 4. per-node BN over (b,c); fills nf half of x, normalizes in place ----
__global__ __launch_bounds__(256) void k_nf_bn(const float* __restrict__ nf,
                                               const float* __restrict__ g3,
                                               const float* __restrict__ b3,
                                               float* __restrict__ x) {
  const int n = blockIdx.x;
  const int tid = threadIdx.x;
  float s = 0.f, s2 = 0.f;
  // go part: 16*64 values
#pragma unroll
  for (int it = 0; it < 4; ++it) {
    int e = it * 256 + tid;
    int b = e >> 6, c = e & 63;
    float v = x[((size_t)(b * kN + n)) * kC + c];
    s += v; s2 += v * v;
  }
  if (tid < 64) {
    float v = nf[n * 64 + tid];
    s += 16.f * v; s2 += 16.f * v * v;
  }
  for (int o = 32; o > 0; o >>= 1) { s += __shfl_down(s, o); s2 += __shfl_down(s2, o); }
  __shared__ float ls[4], ls2[4];
  __shared__ float sscale, sshift;
  const int w = tid >> 6;
  if ((tid & 63) == 0) { ls[w] = s; ls2[w] = s2; }
  __syncthreads();
  if (tid == 0) {
    float S = ls[0] + ls[1] + ls[2] + ls[3];
    float S2 = ls2[0] + ls2[1] + ls2[2] + ls2[3];
    float mean = S * (1.f / 2048.f);
    float var = S2 * (1.f / 2048.f) - mean * mean;
    var = fmaxf(var, 0.f);
    float inv = rsqrtf(var + kEPS);
    float gg = g3[n];
    sscale = inv * gg;
    sshift = b3[n] - mean * inv * gg;
  }
  __syncthreads();
  const float scale = sscale, shift = sshift;
#pragma unroll
  for (int it = 0; it < 8; ++it) {
    int e = it * 256 + tid;
    int b = e >> 7, c = e & 127;
    size_t idx = ((size_t)(b * kN + n)) * kC + c;
    float v = (c < 64) ? x[idx] : nf[n * 64 + (c - 64)];
    x[idx] = v * scale + shift;
  }
}

// ---- 5. qk = x @ [wq|wk] : (16384,128)@(128,128) ----
__global__ __launch_bounds__(256) void k_qk(const float* __restrict__ x,
                                            const float* __restrict__ wq,
                                            const float* __restrict__ wk,
                                            float* __restrict__ qk) {
  __shared__ float a_s[32 * 68];
  __shared__ float w_s[32 * 128];
  const int row0 = blockIdx.x * 32;
  const int tid = threadIdx.x;
  const int tr = tid >> 5, tc = tid & 31;
  const int r0 = tr * 4, c0 = tc * 4;
  float acc[4][4] = {};
  for (int kc = 0; kc < 4; ++kc) {
    const int k0 = kc * 32;
    __syncthreads();
    {  // stage A: 32 rows x 32 k = 256 float4, one per thread
      int r = tid >> 3, kk4 = tid & 7;
      float4 v = *reinterpret_cast<const float4*>(&x[(size_t)(row0 + r) * kC + k0 + kk4 * 4]);
      *reinterpret_cast<float4*>(&a_s[r * 68 + kk4 * 4]) = v;
    }
    for (int it = 0; it < 16; ++it) {  // stage W: 32x128 scalars
      int e = it * 256 + tid;
      int kk = e >> 7, h2 = e & 127;
      int c = k0 + kk;
      float v = (h2 < 64) ? wq[c * 64 + h2] : wk[c * 64 + (h2 - 64)];
      w_s[kk * 128 + h2] = v;
    }
    __syncthreads();
#pragma unroll 8
    for (int k = 0; k < 32; ++k) {
      float a[4];
#pragma unroll
      for (int i = 0; i < 4; ++i) a[i] = a_s[(r0 + i) * 68 + k];
      float4 b4 = *reinterpret_cast<float4*>(&w_s[k * 128 + c0]);
      float bj[4] = {b4.x, b4.y, b4.z, b4.w};
#pragma unroll
      for (int i = 0; i < 4; ++i)
#pragma unroll
        for (int j = 0; j < 4; ++j) acc[i][j] += a[i] * bj[j];
    }
  }
#pragma unroll
  for (int i = 0; i < 4; ++i) {
    float4 o = {acc[i][0], acc[i][1], acc[i][2], acc[i][3]};
    *reinterpret_cast<float4*>(&qk[(size_t)(row0 + r0 + i) * kC + c0]) = o;
  }
}

// ---- 6. att[b,n,m] = q.k / 8 : 64x64 tiles ----
__global__ __launch_bounds__(256) void k_att(const float* __restrict__ qk,
                                             float* __restrict__ att) {
  const int mt = blockIdx.x, nt = blockIdx.y, b = blockIdx.z;
  __shared__ float qs[64 * 65], ks[64 * 65];
  const int tid = threadIdx.x;
  for (int it = 0; it < 16; ++it) {
    int e = it * 256 + tid;
    int r = e >> 6, h = e & 63;
    qs[r * 65 + h] = qk[(size_t)(b * kN + nt * 64 + r) * kC + h];
    ks[r * 65 + h] = qk[(size_t)(b * kN + mt * 64 + r) * kC + 64 + h];
  }
  __syncthreads();
  const int tr = tid >> 4, tc = tid & 15;
  const int r0 = tr * 4, c0 = tc * 4;
  float acc[4][4] = {};
#pragma unroll 8
  for (int k = 0; k < 64; ++k) {
    float a[4], bb[4];
#pragma unroll
    for (int i = 0; i < 4; ++i) a[i] = qs[(r0 + i) * 65 + k];
#pragma unroll
    for (int j = 0; j < 4; ++j) bb[j] = ks[(c0 + j) * 65 + k];
#pragma unroll
    for (int i = 0; i < 4; ++i)
#pragma unroll
      for (int j = 0; j < 4; ++j) acc[i][j] += a[i] * bb[j];
  }
  const float sc = 0.125f;  // 1/sqrt(64)
#pragma unroll
  for (int i = 0; i < 4; ++i) {
    float4 o = {acc[i][0] * sc, acc[i][1] * sc, acc[i][2] * sc, acc[i][3] * sc};
    *reinterpret_cast<float4*>(
        &att[(size_t)(b * kN + nt * 64 + r0 + i) * kN + mt * 64 + c0]) = o;
  }
}

// ---- 7a. column-softmax partial stats (online max/sum over n-chunks) ----
__global__ __launch_bounds__(256) void k_soft_stat(const float* __restrict__ att,
                                                   float* __restrict__ pmax,
                                                   float* __restrict__ psum) {
  const int b = blockIdx.x, ch = blockIdx.y;  // 16 x 16
  const int tid = threadIdx.x;
  const int m0 = tid * 4;
  float mx0 = -1e30f, mx1 = -1e30f, mx2 = -1e30f, mx3 = -1e30f;
  float sm0 = 0.f, sm1 = 0.f, sm2 = 0.f, sm3 = 0.f;
#pragma unroll 2
  for (int n = ch * 64; n < ch * 64 + 64; ++n) {
    float4 v = *reinterpret_cast<const float4*>(&att[(size_t)(b * kN + n) * kN + m0]);
    float nm;
    nm = fmaxf(mx0, v.x); sm0 = sm0 * __expf(mx0 - nm) + __expf(v.x - nm); mx0 = nm;
    nm = fmaxf(mx1, v.y); sm1 = sm1 * __expf(mx1 - nm) + __expf(v.y - nm); mx1 = nm;
    nm = fmaxf(mx2, v.z); sm2 = sm2 * __expf(mx2 - nm) + __expf(v.z - nm); mx2 = nm;
    nm = fmaxf(mx3, v.w); sm3 = sm3 * __expf(mx3 - nm) + __expf(v.w - nm); mx3 = nm;
  }
  const size_t base = (size_t)(b * 16 + ch) * kN + m0;
  float4 pm = {mx0, mx1, mx2, mx3};
  float4 ps = {sm0, sm1, sm2, sm3};
  *reinterpret_cast<float4*>(&pmax[base]) = pm;
  *reinterpret_cast<float4*>(&psum[base]) = ps;
}

// ---- 7b. combine chunk stats -> colmax, 1/colsum ----
__global__ __launch_bounds__(256) void k_soft_comb(const float* __restrict__ pmax,
                                                   const float* __restrict__ psum,
                                                   float* __restrict__ cmax,
                                                   float* __restrict__ cinv) {
  const int i = blockIdx.x * 256 + threadIdx.x;  // 16384
  const int b = i >> 10, m = i & 1023;
  float M = -1e30f;
#pragma unroll
  for (int c = 0; c < 16; ++c) M = fmaxf(M, pmax[(size_t)(b * 16 + c) * kN + m]);
  float S = 0.f;
#pragma unroll
  for (int c = 0; c < 16; ++c)
    S += psum[(size_t)(b * 16 + c) * kN + m] * __expf(pmax[(size_t)(b * 16 + c) * kN + m] - M);
  cmax[i] = M;
  cinv[i] = 1.f / S;
}

// ---- 7c. adj = go_adj + softmax (in place on att) ----
__global__ __launch_bounds__(256) void k_adj(float* __restrict__ att,
                                             const float* __restrict__ go_adj,
                                             const float* __restrict__ cmax,
                                             const float* __restrict__ cinv) {
  const size_t f4 = (size_t)blockIdx.x * 256 + threadIdx.x;  // 4,194,304
  const size_t e = f4 * 4;
  const int b = (int)(e >> 20);
  const int rem = (int)(e & 1048575);
  const int n = rem >> 10, m = rem & 1023;
  float4 v = *reinterpret_cast<float4*>(&att[e]);
  float4 ga = *reinterpret_cast<const float4*>(&go_adj[n * kN + m]);
  float4 M = *reinterpret_cast<const float4*>(&cmax[b * kN + m]);
  float4 I = *reinterpret_cast<const float4*>(&cinv[b * kN + m]);
  v.x = ga.x + __expf(v.x - M.x) * I.x;
  v.y = ga.y + __expf(v.y - M.y) * I.y;
  v.z = ga.z + __expf(v.z - M.z) * I.z;
  v.w = ga.w + __expf(v.w - M.w) * I.w;
  *reinterpret_cast<float4*>(&att[e]) = v;
}

// ---- 8. Y = alpha * adj @ X  (- Zsub if given) : per-batch (1024x1024)@(1024x128) ----
__global__ __launch_bounds__(256) void k_adjmm(const float* __restrict__ adj,
                                               const float* __restrict__ X,
                                               const float* __restrict__ Zsub,
                                               float* __restrict__ Y, float alpha) {
  const int nt = blockIdx.x, b = blockIdx.y;  // 32 x 16
  __shared__ float a_s[32 * 68];
  __shared__ float x_s[64 * 128];
  const int tid = threadIdx.x;
  const int tr = tid >> 5, tc = tid & 31;
  const int r0 = tr * 4, c0 = tc * 4;
  float acc[4][4] = {};
  const float* adjb = adj + (size_t)b * kN * kN;
  for (int kt = 0; kt < 16; ++kt) {
    const int k0 = kt * 64;
    __syncthreads();
#pragma unroll
    for (int it = 0; it < 2; ++it) {  // A tile: 32x64 = 512 float4
      int e4 = it * 256 + tid;
      int r = e4 >> 4, kk4 = e4 & 15;
      float4 v = *reinterpret_cast<const float4*>(&adjb[(size_t)(nt * 32 + r) * kN + k0 + kk4 * 4]);
      *reinterpret_cast<float4*>(&a_s[r * 68 + kk4 * 4]) = v;
    }
#pragma unroll
    for (int it = 0; it < 8; ++it) {  // X tile: 64x128 = 2048 float4
      int e4 = it * 256 + tid;
      int k = e4 >> 5, c4 = e4 & 31;
      float4 v = *reinterpret_cast<const float4*>(&X[(size_t)(b * kN + k0 + k) * kC + c4 * 4]);
      *reinterpret_cast<float4*>(&x_s[k * 128 + c4 * 4]) = v;
    }
    __syncthreads();
#pragma unroll 8
    for (int k = 0; k < 64; ++k) {
      float a[4];
#pragma unroll
      for (int i = 0; i < 4; ++i) a[i] = a_s[(r0 + i) * 68 + k];
      float4 b4 = *reinterpret_cast<float4*>(&x_s[k * 128 + c0]);
      float bj[4] = {b4.x, b4.y, b4.z, b4.w};
#pragma unroll
      for (int i = 0; i < 4; ++i)
#pragma unroll
        for (int j = 0; j < 4; ++j) acc[i][j] += a[i] * bj[j];
    }
  }
#pragma unroll
  for (int i = 0; i < 4; ++i) {
    size_t idx = (size_t)(b * kN + nt * 32 + r0 + i) * kC + c0;
    float4 o = {alpha * acc[i][0], alpha * acc[i][1], alpha * acc[i][2], alpha * acc[i][3]};
    if (Zsub) {
      float4 z = *reinterpret_cast<const float4*>(&Zsub[idx]);
      o.x -= z.x; o.y -= z.y; o.z -= z.z; o.w -= z.w;
    }
    *reinterpret_cast<float4*>(&Y[idx]) = o;
  }
}

// ---- 9. z = x@th0 + tcur@th1 + tnext@th2 + x ----
__global__ __launch_bounds__(256) void k_theta(const float* __restrict__ x,
                                               const float* __restrict__ tcur,
                                               const float* __restrict__ tnext,
                                               const float* __restrict__ theta,
                                               float* __restrict__ z) {
  __shared__ float a_s[32 * 68];
  __shared__ float w_s[32 * 128];
  const int row0 = blockIdx.x * 32;
  const int tid = threadIdx.x;
  const int tr = tid >> 5, tc = tid & 31;
  const int r0 = tr * 4, c0 = tc * 4;
  float acc[4][4] = {};
  const float* srcs[3] = {x, tcur, tnext};
  for (int s = 0; s < 3; ++s) {
    const float* A = srcs[s];
    for (int kc = 0; kc < 4; ++kc) {
      const int k0 = kc * 32;
      __syncthreads();
      {  // stage A: 32x32 = 256 float4
        int r = tid >> 3, kk4 = tid & 7;
        float4 v = *reinterpret_cast<const float4*>(&A[(size_t)(row0 + r) * kC + k0 + kk4 * 4]);
        *reinterpret_cast<float4*>(&a_s[r * 68 + kk4 * 4]) = v;
      }
#pragma unroll
      for (int it = 0; it < 4; ++it) {  // stage W: 32x128 = 1024 float4
        int e4 = it * 256 + tid;
        int kk = e4 >> 5, d4 = e4 & 31;
        float4 v = *reinterpret_cast<const float4*>(
            &theta[(size_t)s * 16384 + (size_t)(k0 + kk) * kC + d4 * 4]);
        *reinterpret_cast<float4*>(&w_s[kk * 128 + d4 * 4]) = v;
      }
      __syncthreads();
#pragma unroll 8
      for (int k = 0; k < 32; ++k) {
        float a[4];
#pragma unroll
        for (int i = 0; i < 4; ++i) a[i] = a_s[(r0 + i) * 68 + k];
        float4 b4 = *reinterpret_cast<float4*>(&w_s[k * 128 + c0]);
        float bj[4] = {b4.x, b4.y, b4.z, b4.w};
#pragma unroll
        for (int i = 0; i < 4; ++i)
#pragma unroll
          for (int j = 0; j < 4; ++j) acc[i][j] += a[i] * bj[j];
      }
    }
  }
#pragma unroll
  for (int i = 0; i < 4; ++i) {
    size_t idx = (size_t)(row0 + r0 + i) * kC + c0;
    float4 xv = *reinterpret_cast<const float4*>(&x[idx]);
    float4 o = {acc[i][0] + xv.x, acc[i][1] + xv.y, acc[i][2] + xv.z, acc[i][3] + xv.w};
    *reinterpret_cast<float4*>(&z[idx]) = o;
  }
}

// ---- 10. per-node BN + relu + dot(w_out) -> out (16,1024) ----
__global__ __launch_bounds__(256) void k_final(const float* __restrict__ z,
                                               const float* __restrict__ g4,
                                               const float* __restrict__ b4v,
                                               const float* __restrict__ w_out,
                                               const float* __restrict__ b_out,
                                               float* __restrict__ out) {
  const int n = blockIdx.x;
  const int tid = threadIdx.x;
  float s = 0.f, s2 = 0.f;
#pragma unroll
  for (int it = 0; it < 8; ++it) {
    int e = it * 256 + tid;
    int b = e >> 7, c = e & 127;
    float v = z[(size_t)(b * kN + n) * kC + c];
    s += v; s2 += v * v;
  }
  for (int o = 32; o > 0; o >>= 1) { s += __shfl_down(s, o); s2 += __shfl_down(s2, o); }
  __shared__ float ls[4], ls2[4];
  __shared__ float sscale, sshift;
  const int w = tid >> 6;
  if ((tid & 63) == 0) { ls[w] = s; ls2[w] = s2; }
  __syncthreads();
  if (tid == 0) {
    float S = ls[0] + ls[1] + ls[2] + ls[3];
    float S2 = ls2[0] + ls2[1] + ls2[2] + ls2[3];
    float mean = S * (1.f / 2048.f);
    float var = S2 * (1.f / 2048.f) - mean * mean;
    var = fmaxf(var, 0.f);
    float inv = rsqrtf(var + kEPS);
    float gg = g4[n];
    sscale = inv * gg;
    sshift = b4v[n] - mean * inv * gg;
  }
  __syncthreads();
  const float scale = sscale, shift = sshift;
  const int b = tid >> 4, c0 = (tid & 15) * 8;
  float p = 0.f;
#pragma unroll
  for (int j = 0; j < 8; ++j) {
    float v = z[(size_t)(b * kN + n) * kC + c0 + j] * scale + shift;
    v = fmaxf(v, 0.f);
    p += v * w_out[c0 + j];
  }
  for (int o = 8; o > 0; o >>= 1) p += __shfl_down(p, o, 16);
  if ((tid & 15) == 0) out[b * kN + n] = p + b_out[0];
}

extern "C" void kernel_launch(void* const* d_in, const int* in_sizes, int n_in,
                              void* d_out, int out_size, void* d_ws, size_t ws_size,
                              hipStream_t stream) {
  const int*   data = (const int*)d_in[0];
  const float* node_features = (const float*)d_in[1];
  const float* go_adj = (const float*)d_in[2];
  const float* emb  = (const float*)d_in[4];
  const float* w_go = (const float*)d_in[5];
  const float* b_go = (const float*)d_in[6];
  const float* wq   = (const float*)d_in[7];
  const float* wk   = (const float*)d_in[8];
  const float* theta= (const float*)d_in[9];
  const float* g1   = (const float*)d_in[10];
  const float* b1   = (const float*)d_in[11];
  const float* g3   = (const float*)d_in[12];
  const float* b3   = (const float*)d_in[13];
  const float* g4   = (const float*)d_in[14];
  const float* b4   = (const float*)d_in[15];
  const float* w_out= (const float*)d_in[16];
  const float* b_out= (const float*)d_in[17];

  float* ws = (float*)d_ws;
  float* featpart = ws + OFF_FEATPART;
  float* m1    = ws + OFF_M1;
  float* x     = ws + OFF_X;
  float* qk    = ws + OFF_QK;   // reused as z later
  float* tcur  = ws + OFF_TCUR;
  float* tnext = ws + OFF_TNEXT;
  float* att   = ws + OFF_ATT;
  float* pmax  = ws + OFF_PMAX;
  float* psum  = ws + OFF_PSUM;
  float* cmax  = ws + OFF_CMAX;
  float* cinv  = ws + OFF_CINV;

  k_embsum<<<dim3(16, 8), 256, 0, stream>>>(data, emb, featpart);
  k_bn_feat<<<1, 512, 0, stream>>>(featpart, data, g1, b1, m1);
  k_go_gemm<<<256, 256, 0, stream>>>(m1, w_go, b_go, x);
  k_nf_bn<<<1024, 256, 0, stream>>>(node_features, g3, b3, x);
  k_qk<<<512, 256, 0, stream>>>(x, wq, wk, qk);
  k_att<<<dim3(16, 16, 16), 256, 0, stream>>>(qk, att);
  k_soft_stat<<<dim3(16, 16), 256, 0, stream>>>(att, pmax, psum);
  k_soft_comb<<<64, 256, 0, stream>>>(pmax, psum, cmax, cinv);
  k_adj<<<16384, 256, 0, stream>>>(att, go_adj, cmax, cinv);
  k_adjmm<<<dim3(32, 16), 256, 0, stream>>>(att, x, nullptr, tcur, 1.0f);
  k_adjmm<<<dim3(32, 16), 256, 0, stream>>>(att, tcur, x, tnext, 2.0f);
  k_theta<<<512, 256, 0, stream>>>(x, tcur, tnext, theta, qk /* z */);
  k_final<<<1024, 256, 0, stream>>>(qk, g4, b4, w_out, b_out, (float*)d_out);
}

// Round 2
// 349.794 us; speedup vs baseline: 1.0197x; 1.0197x over previous
//
#include <hip/hip_runtime.h>

namespace {
constexpr int kB = 16;
constexpr int kMAXLEN = 1024;
constexpr int kPE = 256;
constexpr int kN = 1024;
constexpr int kEMB = 256;
constexpr int kC = 128;
constexpr float kEPS = 1e-5f;

// workspace offsets in floats
constexpr size_t OFF_FEATPART = 0;                       // 16*8*256 = 32768
constexpr size_t OFF_M1       = 32768;                   // m1t transposed: 512*16 = 8192
constexpr size_t OFF_X        = 65536;                   // 16*1024*128 = 2097152
constexpr size_t OFF_QK       = OFF_X   + 2097152;       // q|k, later reused as z
constexpr size_t OFF_TCUR     = OFF_QK  + 2097152;
constexpr size_t OFF_TNEXT    = OFF_TCUR+ 2097152;
constexpr size_t OFF_ATT      = OFF_TNEXT+2097152;       // 16*1024*1024 (also go-partials early)
constexpr size_t OFF_PMAX     = OFF_ATT + 16777216;      // 16*16*1024
constexpr size_t OFF_PSUM     = OFF_PMAX+ 262144;
constexpr size_t OFF_CMAX     = OFF_PSUM+ 262144;        // 16*1024
constexpr size_t OFF_CINV     = OFF_CMAX+ 16384;
} // namespace

// ---- 1. embedding gather partial sums: featpart[b][chunk][e] ----
__global__ __launch_bounds__(256) void k_embsum(const int* __restrict__ data,
                                                const float* __restrict__ emb,
                                                float* __restrict__ featpart) {
  const int b = blockIdx.x, ch = blockIdx.y;   // 16 x 8
  const int e = threadIdx.x;                   // 256
  const int* row = data + b * (kMAXLEN + kPE) + ch * 128;
  float acc = 0.f;
#pragma unroll 4
  for (int l = 0; l < 128; ++l) {
    acc += emb[(size_t)row[l] * kEMB + e];
  }
  featpart[((b * 8 + ch) << 8) + e] = acc;
}

// ---- 2. BN over batch of concat[feat, inp2] -> m1t (512,16) TRANSPOSED ----
__global__ __launch_bounds__(512) void k_bn_feat(const float* __restrict__ featpart,
                                                 const int* __restrict__ data,
                                                 const float* __restrict__ g1,
                                                 const float* __restrict__ b1,
                                                 float* __restrict__ m1t) {
  const int j = threadIdx.x;  // 0..511 (feature index k)
  float v[kB];
  if (j < kPE) {
    const float pe = sinf((float)j);
#pragma unroll
    for (int b = 0; b < kB; ++b) {
      float s = 0.f;
      for (int ch = 0; ch < 8; ++ch) s += featpart[((b * 8 + ch) << 8) + j];
      v[b] = s * (1.f / 1024.f) + pe;
    }
  } else {
    const int e = j - kPE;
    const float pe = sinf((float)e);
#pragma unroll
    for (int b = 0; b < kB; ++b)
      v[b] = (float)data[b * (kMAXLEN + kPE) + kMAXLEN + e] + pe;
  }
  float s = 0.f;
#pragma unroll
  for (int b = 0; b < kB; ++b) s += v[b];
  const float mean = s * (1.f / kB);
  float s2 = 0.f;
#pragma unroll
  for (int b = 0; b < kB; ++b) { float d = v[b] - mean; s2 += d * d; }
  const float inv = rsqrtf(s2 * (1.f / kB) + kEPS);
  const float g = g1[j], bb = b1[j];
#pragma unroll
  for (int b = 0; b < kB; ++b) m1t[j * kB + b] = (v[b] - mean) * inv * g + bb;
}

// ---- 3a. split-K GEMM: part[kb][b][col] = sum_{k in kb} m1t[k][b]*w_go[k][col] ----
// grid (64, 4), block 256. Thread owns 4 cols (float4). m1t read via uniform
// scalar loads (SGPR broadcast) -> zero LDS traffic in the hot loop.
__global__ __launch_bounds__(256) void k_go_gemm2(const float* __restrict__ m1t,
                                                  const float* __restrict__ w_go,
                                                  float* __restrict__ part) {
  const int c0 = blockIdx.x * 1024 + threadIdx.x * 4;   // column base
  const int k0 = blockIdx.y * 128;                      // k-slice base
  float4 acc[kB];
#pragma unroll
  for (int b = 0; b < kB; ++b) acc[b] = make_float4(0.f, 0.f, 0.f, 0.f);
#pragma unroll 4
  for (int k = 0; k < 128; ++k) {
    const float4 w = *reinterpret_cast<const float4*>(&w_go[(size_t)(k0 + k) * 65536 + c0]);
    const float* mrow = m1t + (size_t)(k0 + k) * kB;   // uniform address -> s_load
#pragma unroll
    for (int b = 0; b < kB; ++b) {
      const float m = mrow[b];
      acc[b].x += m * w.x; acc[b].y += m * w.y;
      acc[b].z += m * w.z; acc[b].w += m * w.w;
    }
  }
  const size_t kb16 = (size_t)blockIdx.y * kB;
#pragma unroll
  for (int b = 0; b < kB; ++b) {
    *reinterpret_cast<float4*>(&part[(kb16 + b) * 65536 + c0]) = acc[b];
  }
}

// ---- 3b. reduce partials + bias + relu -> x[...,0:64] ----
__global__ __launch_bounds__(256) void k_go_reduce(const float* __restrict__ part,
                                                   const float* __restrict__ b_go,
                                                   float* __restrict__ x) {
  const int g = blockIdx.x * 256 + threadIdx.x;  // 0..262143 float4 ids
  const int b = g >> 14;                          // /16384
  const int cw = g & 16383;
  const int col = cw * 4;
  float4 a = *reinterpret_cast<const float4*>(&part[(size_t)b * 65536 + col]);
#pragma unroll
  for (int kb = 1; kb < 4; ++kb) {
    float4 p = *reinterpret_cast<const float4*>(&part[(size_t)(kb * kB + b) * 65536 + col]);
    a.x += p.x; a.y += p.y; a.z += p.z; a.w += p.w;
  }
  const float4 bg = *reinterpret_cast<const float4*>(&b_go[col]);
  a.x = fmaxf(a.x + bg.x, 0.f); a.y = fmaxf(a.y + bg.y, 0.f);
  a.z = fmaxf(a.z + bg.z, 0.f); a.w = fmaxf(a.w + bg.w, 0.f);
  const int n = col >> 6, c = col & 63;
  *reinterpret_cast<float4*>(&x[((size_t)(b * kN + n)) * kC + c]) = a;
}

// ---- 4. per-node BN over (b,c); fills nf half of x, normalizes in place ----
__global__ __launch_bounds__(256) void k_nf_bn(const float* __restrict__ nf,
                                               const float* __restrict__ g3,
                                               const float* __restrict__ b3,
                                               float* __restrict__ x) {
  const int n = blockIdx.x;
  const int tid = threadIdx.x;
  float s = 0.f, s2 = 0.f;
#pragma unroll
  for (int it = 0; it < 4; ++it) {
    int e = it * 256 + tid;
    int b = e >> 6, c = e & 63;
    float v = x[((size_t)(b * kN + n)) * kC + c];
    s += v; s2 += v * v;
  }
  if (tid < 64) {
    float v = nf[n * 64 + tid];
    s += 16.f * v; s2 += 16.f * v * v;
  }
  for (int o = 32; o > 0; o >>= 1) { s += __shfl_down(s, o); s2 += __shfl_down(s2, o); }
  __shared__ float ls[4], ls2[4];
  __shared__ float sscale, sshift;
  const int w = tid >> 6;
  if ((tid & 63) == 0) { ls[w] = s; ls2[w] = s2; }
  __syncthreads();
  if (tid == 0) {
    float S = ls[0] + ls[1] + ls[2] + ls[3];
    float S2 = ls2[0] + ls2[1] + ls2[2] + ls2[3];
    float mean = S * (1.f / 2048.f);
    float var = S2 * (1.f / 2048.f) - mean * mean;
    var = fmaxf(var, 0.f);
    float inv = rsqrtf(var + kEPS);
    float gg = g3[n];
    sscale = inv * gg;
    sshift = b3[n] - mean * inv * gg;
  }
  __syncthreads();
  const float scale = sscale, shift = sshift;
#pragma unroll
  for (int it = 0; it < 8; ++it) {
    int e = it * 256 + tid;
    int b = e >> 7, c = e & 127;
    size_t idx = ((size_t)(b * kN + n)) * kC + c;
    float v = (c < 64) ? x[idx] : nf[n * 64 + (c - 64)];
    x[idx] = v * scale + shift;
  }
}

// ---- 5. qk = x @ [wq|wk] : (16384,128)@(128,128) ----
__global__ __launch_bounds__(256) void k_qk(const float* __restrict__ x,
                                            const float* __restrict__ wq,
                                            const float* __restrict__ wk,
                                            float* __restrict__ qk) {
  __shared__ float a_s[32 * 68];
  __shared__ float w_s[32 * 128];
  const int row0 = blockIdx.x * 32;
  const int tid = threadIdx.x;
  const int tr = tid >> 5, tc = tid & 31;
  const int r0 = tr * 4, c0 = tc * 4;
  float acc[4][4] = {};
  for (int kc = 0; kc < 4; ++kc) {
    const int k0 = kc * 32;
    __syncthreads();
    {  // stage A: 32 rows x 32 k = 256 float4, one per thread
      int r = tid >> 3, kk4 = tid & 7;
      float4 v = *reinterpret_cast<const float4*>(&x[(size_t)(row0 + r) * kC + k0 + kk4 * 4]);
      *reinterpret_cast<float4*>(&a_s[r * 68 + kk4 * 4]) = v;
    }
    for (int it = 0; it < 16; ++it) {  // stage W: 32x128 scalars
      int e = it * 256 + tid;
      int kk = e >> 7, h2 = e & 127;
      int c = k0 + kk;
      float v = (h2 < 64) ? wq[c * 64 + h2] : wk[c * 64 + (h2 - 64)];
      w_s[kk * 128 + h2] = v;
    }
    __syncthreads();
#pragma unroll 8
    for (int k = 0; k < 32; ++k) {
      float a[4];
#pragma unroll
      for (int i = 0; i < 4; ++i) a[i] = a_s[(r0 + i) * 68 + k];
      float4 b4 = *reinterpret_cast<float4*>(&w_s[k * 128 + c0]);
      float bj[4] = {b4.x, b4.y, b4.z, b4.w};
#pragma unroll
      for (int i = 0; i < 4; ++i)
#pragma unroll
        for (int j = 0; j < 4; ++j) acc[i][j] += a[i] * bj[j];
    }
  }
#pragma unroll
  for (int i = 0; i < 4; ++i) {
    float4 o = {acc[i][0], acc[i][1], acc[i][2], acc[i][3]};
    *reinterpret_cast<float4*>(&qk[(size_t)(row0 + r0 + i) * kC + c0]) = o;
  }
}

// ---- 6. att[b,n,m] = q.k / 8 : 64x64 tiles ----
__global__ __launch_bounds__(256) void k_att(const float* __restrict__ qk,
                                             float* __restrict__ att) {
  const int mt = blockIdx.x, nt = blockIdx.y, b = blockIdx.z;
  __shared__ float qs[64 * 65], ks[64 * 65];
  const int tid = threadIdx.x;
  for (int it = 0; it < 16; ++it) {
    int e = it * 256 + tid;
    int r = e >> 6, h = e & 63;
    qs[r * 65 + h] = qk[(size_t)(b * kN + nt * 64 + r) * kC + h];
    ks[r * 65 + h] = qk[(size_t)(b * kN + mt * 64 + r) * kC + 64 + h];
  }
  __syncthreads();
  const int tr = tid >> 4, tc = tid & 15;
  const int r0 = tr * 4, c0 = tc * 4;
  float acc[4][4] = {};
#pragma unroll 8
  for (int k = 0; k < 64; ++k) {
    float a[4], bb[4];
#pragma unroll
    for (int i = 0; i < 4; ++i) a[i] = qs[(r0 + i) * 65 + k];
#pragma unroll
    for (int j = 0; j < 4; ++j) bb[j] = ks[(c0 + j) * 65 + k];
#pragma unroll
    for (int i = 0; i < 4; ++i)
#pragma unroll
      for (int j = 0; j < 4; ++j) acc[i][j] += a[i] * bb[j];
  }
  const float sc = 0.125f;  // 1/sqrt(64)
#pragma unroll
  for (int i = 0; i < 4; ++i) {
    float4 o = {acc[i][0] * sc, acc[i][1] * sc, acc[i][2] * sc, acc[i][3] * sc};
    *reinterpret_cast<float4*>(
        &att[(size_t)(b * kN + nt * 64 + r0 + i) * kN + mt * 64 + c0]) = o;
  }
}

// ---- 7a. column-softmax partial stats (online max/sum over n-chunks) ----
__global__ __launch_bounds__(256) void k_soft_stat(const float* __restrict__ att,
                                                   float* __restrict__ pmax,
                                                   float* __restrict__ psum) {
  const int b = blockIdx.x, ch = blockIdx.y;  // 16 x 16
  const int tid = threadIdx.x;
  const int m0 = tid * 4;
  float mx0 = -1e30f, mx1 = -1e30f, mx2 = -1e30f, mx3 = -1e30f;
  float sm0 = 0.f, sm1 = 0.f, sm2 = 0.f, sm3 = 0.f;
#pragma unroll 2
  for (int n = ch * 64; n < ch * 64 + 64; ++n) {
    float4 v = *reinterpret_cast<const float4*>(&att[(size_t)(b * kN + n) * kN + m0]);
    float nm;
    nm = fmaxf(mx0, v.x); sm0 = sm0 * __expf(mx0 - nm) + __expf(v.x - nm); mx0 = nm;
    nm = fmaxf(mx1, v.y); sm1 = sm1 * __expf(mx1 - nm) + __expf(v.y - nm); mx1 = nm;
    nm = fmaxf(mx2, v.z); sm2 = sm2 * __expf(mx2 - nm) + __expf(v.z - nm); mx2 = nm;
    nm = fmaxf(mx3, v.w); sm3 = sm3 * __expf(mx3 - nm) + __expf(v.w - nm); mx3 = nm;
  }
  const size_t base = (size_t)(b * 16 + ch) * kN + m0;
  float4 pm = {mx0, mx1, mx2, mx3};
  float4 ps = {sm0, sm1, sm2, sm3};
  *reinterpret_cast<float4*>(&pmax[base]) = pm;
  *reinterpret_cast<float4*>(&psum[base]) = ps;
}

// ---- 7b. combine chunk stats -> colmax, 1/colsum ----
__global__ __launch_bounds__(256) void k_soft_comb(const float* __restrict__ pmax,
                                                   const float* __restrict__ psum,
                                                   float* __restrict__ cmax,
                                                   float* __restrict__ cinv) {
  const int i = blockIdx.x * 256 + threadIdx.x;  // 16384
  const int b = i >> 10, m = i & 1023;
  float M = -1e30f;
#pragma unroll
  for (int c = 0; c < 16; ++c) M = fmaxf(M, pmax[(size_t)(b * 16 + c) * kN + m]);
  float S = 0.f;
#pragma unroll
  for (int c = 0; c < 16; ++c)
    S += psum[(size_t)(b * 16 + c) * kN + m] * __expf(pmax[(size_t)(b * 16 + c) * kN + m] - M);
  cmax[i] = M;
  cinv[i] = 1.f / S;
}

// ---- 7c. adj = go_adj + softmax (in place on att) ----
__global__ __launch_bounds__(256) void k_adj(float* __restrict__ att,
                                             const float* __restrict__ go_adj,
                                             const float* __restrict__ cmax,
                                             const float* __restrict__ cinv) {
  const size_t f4 = (size_t)blockIdx.x * 256 + threadIdx.x;  // 4,194,304
  const size_t e = f4 * 4;
  const int b = (int)(e >> 20);
  const int rem = (int)(e & 1048575);
  const int n = rem >> 10, m = rem & 1023;
  float4 v = *reinterpret_cast<float4*>(&att[e]);
  float4 ga = *reinterpret_cast<const float4*>(&go_adj[n * kN + m]);
  float4 M = *reinterpret_cast<const float4*>(&cmax[b * kN + m]);
  float4 I = *reinterpret_cast<const float4*>(&cinv[b * kN + m]);
  v.x = ga.x + __expf(v.x - M.x) * I.x;
  v.y = ga.y + __expf(v.y - M.y) * I.y;
  v.z = ga.z + __expf(v.z - M.z) * I.z;
  v.w = ga.w + __expf(v.w - M.w) * I.w;
  *reinterpret_cast<float4*>(&att[e]) = v;
}

// ---- 8. Y = alpha * adj @ X  (- Zsub if given) : per-batch (1024x1024)@(1024x128) ----
__global__ __launch_bounds__(256) void k_adjmm(const float* __restrict__ adj,
                                               const float* __restrict__ X,
                                               const float* __restrict__ Zsub,
                                               float* __restrict__ Y, float alpha) {
  const int nt = blockIdx.x, b = blockIdx.y;  // 32 x 16
  __shared__ float a_s[32 * 68];
  __shared__ float x_s[64 * 128];
  const int tid = threadIdx.x;
  const int tr = tid >> 5, tc = tid & 31;
  const int r0 = tr * 4, c0 = tc * 4;
  float acc[4][4] = {};
  const float* adjb = adj + (size_t)b * kN * kN;
  for (int kt = 0; kt < 16; ++kt) {
    const int k0 = kt * 64;
    __syncthreads();
#pragma unroll
    for (int it = 0; it < 2; ++it) {  // A tile: 32x64 = 512 float4
      int e4 = it * 256 + tid;
      int r = e4 >> 4, kk4 = e4 & 15;
      float4 v = *reinterpret_cast<const float4*>(&adjb[(size_t)(nt * 32 + r) * kN + k0 + kk4 * 4]);
      *reinterpret_cast<float4*>(&a_s[r * 68 + kk4 * 4]) = v;
    }
#pragma unroll
    for (int it = 0; it < 8; ++it) {  // X tile: 64x128 = 2048 float4
      int e4 = it * 256 + tid;
      int k = e4 >> 5, c4 = e4 & 31;
      float4 v = *reinterpret_cast<const float4*>(&X[(size_t)(b * kN + k0 + k) * kC + c4 * 4]);
      *reinterpret_cast<float4*>(&x_s[k * 128 + c4 * 4]) = v;
    }
    __syncthreads();
#pragma unroll 8
    for (int k = 0; k < 64; ++k) {
      float a[4];
#pragma unroll
      for (int i = 0; i < 4; ++i) a[i] = a_s[(r0 + i) * 68 + k];
      float4 b4 = *reinterpret_cast<float4*>(&x_s[k * 128 + c0]);
      float bj[4] = {b4.x, b4.y, b4.z, b4.w};
#pragma unroll
      for (int i = 0; i < 4; ++i)
#pragma unroll
        for (int j = 0; j < 4; ++j) acc[i][j] += a[i] * bj[j];
    }
  }
#pragma unroll
  for (int i = 0; i < 4; ++i) {
    size_t idx = (size_t)(b * kN + nt * 32 + r0 + i) * kC + c0;
    float4 o = {alpha * acc[i][0], alpha * acc[i][1], alpha * acc[i][2], alpha * acc[i][3]};
    if (Zsub) {
      float4 z = *reinterpret_cast<const float4*>(&Zsub[idx]);
      o.x -= z.x; o.y -= z.y; o.z -= z.z; o.w -= z.w;
    }
    *reinterpret_cast<float4*>(&Y[idx]) = o;
  }
}

// ---- 9. z = x@th0 + tcur@th1 + tnext@th2 + x ----
__global__ __launch_bounds__(256) void k_theta(const float* __restrict__ x,
                                               const float* __restrict__ tcur,
                                               const float* __restrict__ tnext,
                                               const float* __restrict__ theta,
                                               float* __restrict__ z) {
  __shared__ float a_s[32 * 68];
  __shared__ float w_s[32 * 128];
  const int row0 = blockIdx.x * 32;
  const int tid = threadIdx.x;
  const int tr = tid >> 5, tc = tid & 31;
  const int r0 = tr * 4, c0 = tc * 4;
  float acc[4][4] = {};
  const float* srcs[3] = {x, tcur, tnext};
  for (int s = 0; s < 3; ++s) {
    const float* A = srcs[s];
    for (int kc = 0; kc < 4; ++kc) {
      const int k0 = kc * 32;
      __syncthreads();
      {  // stage A: 32x32 = 256 float4
        int r = tid >> 3, kk4 = tid & 7;
        float4 v = *reinterpret_cast<const float4*>(&A[(size_t)(row0 + r) * kC + k0 + kk4 * 4]);
        *reinterpret_cast<float4*>(&a_s[r * 68 + kk4 * 4]) = v;
      }
#pragma unroll
      for (int it = 0; it < 4; ++it) {  // stage W: 32x128 = 1024 float4
        int e4 = it * 256 + tid;
        int kk = e4 >> 5, d4 = e4 & 31;
        float4 v = *reinterpret_cast<const float4*>(
            &theta[(size_t)s * 16384 + (size_t)(k0 + kk) * kC + d4 * 4]);
        *reinterpret_cast<float4*>(&w_s[kk * 128 + d4 * 4]) = v;
      }
      __syncthreads();
#pragma unroll 8
      for (int k = 0; k < 32; ++k) {
        float a[4];
#pragma unroll
        for (int i = 0; i < 4; ++i) a[i] = a_s[(r0 + i) * 68 + k];
        float4 b4 = *reinterpret_cast<float4*>(&w_s[k * 128 + c0]);
        float bj[4] = {b4.x, b4.y, b4.z, b4.w};
#pragma unroll
        for (int i = 0; i < 4; ++i)
#pragma unroll
          for (int j = 0; j < 4; ++j) acc[i][j] += a[i] * bj[j];
      }
    }
  }
#pragma unroll
  for (int i = 0; i < 4; ++i) {
    size_t idx = (size_t)(row0 + r0 + i) * kC + c0;
    float4 xv = *reinterpret_cast<const float4*>(&x[idx]);
    float4 o = {acc[i][0] + xv.x, acc[i][1] + xv.y, acc[i][2] + xv.z, acc[i][3] + xv.w};
    *reinterpret_cast<float4*>(&z[idx]) = o;
  }
}

// ---- 10. per-node BN + relu + dot(w_out) -> out (16,1024) ----
__global__ __launch_bounds__(256) void k_final(const float* __restrict__ z,
                                               const float* __restrict__ g4,
                                               const float* __restrict__ b4v,
                                               const float* __restrict__ w_out,
                                               const float* __restrict__ b_out,
                                               float* __restrict__ out) {
  const int n = blockIdx.x;
  const int tid = threadIdx.x;
  float s = 0.f, s2 = 0.f;
#pragma unroll
  for (int it = 0; it < 8; ++it) {
    int e = it * 256 + tid;
    int b = e >> 7, c = e & 127;
    float v = z[(size_t)(b * kN + n) * kC + c];
    s += v; s2 += v * v;
  }
  for (int o = 32; o > 0; o >>= 1) { s += __shfl_down(s, o); s2 += __shfl_down(s2, o); }
  __shared__ float ls[4], ls2[4];
  __shared__ float sscale, sshift;
  const int w = tid >> 6;
  if ((tid & 63) == 0) { ls[w] = s; ls2[w] = s2; }
  __syncthreads();
  if (tid == 0) {
    float S = ls[0] + ls[1] + ls[2] + ls[3];
    float S2 = ls2[0] + ls2[1] + ls2[2] + ls2[3];
    float mean = S * (1.f / 2048.f);
    float var = S2 * (1.f / 2048.f) - mean * mean;
    var = fmaxf(var, 0.f);
    float inv = rsqrtf(var + kEPS);
    float gg = g4[n];
    sscale = inv * gg;
    sshift = b4v[n] - mean * inv * gg;
  }
  __syncthreads();
  const float scale = sscale, shift = sshift;
  const int b = tid >> 4, c0 = (tid & 15) * 8;
  float p = 0.f;
#pragma unroll
  for (int j = 0; j < 8; ++j) {
    float v = z[(size_t)(b * kN + n) * kC + c0 + j] * scale + shift;
    v = fmaxf(v, 0.f);
    p += v * w_out[c0 + j];
  }
  for (int o = 8; o > 0; o >>= 1) p += __shfl_down(p, o, 16);
  if ((tid & 15) == 0) out[b * kN + n] = p + b_out[0];
}

extern "C" void kernel_launch(void* const* d_in, const int* in_sizes, int n_in,
                              void* d_out, int out_size, void* d_ws, size_t ws_size,
                              hipStream_t stream) {
  const int*   data = (const int*)d_in[0];
  const float* node_features = (const float*)d_in[1];
  const float* go_adj = (const float*)d_in[2];
  const float* emb  = (const float*)d_in[4];
  const float* w_go = (const float*)d_in[5];
  const float* b_go = (const float*)d_in[6];
  const float* wq   = (const float*)d_in[7];
  const float* wk   = (const float*)d_in[8];
  const float* theta= (const float*)d_in[9];
  const float* g1   = (const float*)d_in[10];
  const float* b1   = (const float*)d_in[11];
  const float* g3   = (const float*)d_in[12];
  const float* b3   = (const float*)d_in[13];
  const float* g4   = (const float*)d_in[14];
  const float* b4   = (const float*)d_in[15];
  const float* w_out= (const float*)d_in[16];
  const float* b_out= (const float*)d_in[17];

  float* ws = (float*)d_ws;
  float* featpart = ws + OFF_FEATPART;
  float* m1t   = ws + OFF_M1;
  float* x     = ws + OFF_X;
  float* qk    = ws + OFF_QK;   // reused as z later
  float* tcur  = ws + OFF_TCUR;
  float* tnext = ws + OFF_TNEXT;
  float* att   = ws + OFF_ATT;  // go-partials alias this region early
  float* pmax  = ws + OFF_PMAX;
  float* psum  = ws + OFF_PSUM;
  float* cmax  = ws + OFF_CMAX;
  float* cinv  = ws + OFF_CINV;

  k_embsum<<<dim3(16, 8), 256, 0, stream>>>(data, emb, featpart);
  k_bn_feat<<<1, 512, 0, stream>>>(featpart, data, g1, b1, m1t);
  k_go_gemm2<<<dim3(64, 4), 256, 0, stream>>>(m1t, w_go, att /* partials */);
  k_go_reduce<<<1024, 256, 0, stream>>>(att /* partials */, b_go, x);
  k_nf_bn<<<1024, 256, 0, stream>>>(node_features, g3, b3, x);
  k_qk<<<512, 256, 0, stream>>>(x, wq, wk, qk);
  k_att<<<dim3(16, 16, 16), 256, 0, stream>>>(qk, att);
  k_soft_stat<<<dim3(16, 16), 256, 0, stream>>>(att, pmax, psum);
  k_soft_comb<<<64, 256, 0, stream>>>(pmax, psum, cmax, cinv);
  k_adj<<<16384, 256, 0, stream>>>(att, go_adj, cmax, cinv);
  k_adjmm<<<dim3(32, 16), 256, 0, stream>>>(att, x, nullptr, tcur, 1.0f);
  k_adjmm<<<dim3(32, 16), 256, 0, stream>>>(att, tcur, x, tnext, 2.0f);
  k_theta<<<512, 256, 0, stream>>>(x, tcur, tnext, theta, qk /* z */);
  k_final<<<1024, 256, 0, stream>>>(qk, g4, b4, w_out, b_out, (float*)d_out);
}